// Round 9
// baseline (397.557 us; speedup 1.0000x reference)
//
#include <hip/hip_runtime.h>
#include <hip/hip_bf16.h>

#define NN 50000      // nodes
#define NE 800000     // edges
#define NR 20         // relations
#define NB 8          // bases
#define D  128        // hidden dim
#define DO 64         // output dim
#define NT 782        // ceil(NN/64) dst tiles
#define NBKT (NT*1280) // (tile, rel, dl) buckets = 1,000,960
#define NSB 978       // ceil(NBKT/1024)

typedef __attribute__((ext_vector_type(8))) short short8;
typedef __attribute__((ext_vector_type(4))) float f32x4;

__device__ inline unsigned short f2bf(float f) {
    __hip_bfloat16 h = __float2bfloat16(f);
    return *reinterpret_cast<unsigned short*>(&h);
}
__device__ inline float bf2f(unsigned short u) {
    unsigned x = ((unsigned)u) << 16;
    float f;
    __builtin_memcpy(&f, &x, 4);
    return f;
}

// async global->LDS, 16 B per lane; LDS dest = (wave-uniform) l + lane*16,
// global src is per-lane (pre-swizzle goes on the SOURCE address).
__device__ __forceinline__ void gload16(const void* g, void* l) {
    __builtin_amdgcn_global_load_lds(
        (const __attribute__((address_space(1))) unsigned int*)g,
        (__attribute__((address_space(3))) unsigned int*)l, 16, 0, 0);
}

// ---------------------------------------------------------------------------
// ws layout (bytes): unchanged from r8
//   [0        ..  4,003,840) cnt2  | [4,003,840.. 4,007,752) bsum
//   [4,007,808..  8,011,652) boff2 | [8,011,712..12,015,552) gcur2
//   [12,015,616..12,025,856) W0    | [12,025,856..12,681,216) W1b
//   [12,681,216..25,481,216) h1b   | [25,481,216..28,681,216) epack
// ---------------------------------------------------------------------------

__global__ __launch_bounds__(256) void k_weights(
        const float* __restrict__ basis0, const float* __restrict__ wcomp0,
        const float* __restrict__ basis1, const float* __restrict__ wcomp1,
        float* __restrict__ W0, unsigned short* __restrict__ W1b) {
    int idx = blockIdx.x * 256 + threadIdx.x;   // 0..40959
    if (idx < NR * D) {
        int r = idx / D, o = idx % D;
        float a = 0.f;
        #pragma unroll
        for (int b = 0; b < NB; b++) a += wcomp0[r * NB + b] * basis0[b * D + o];
        W0[idx] = a;
    }
    if (idx < NR * 4 * 8 * 64) {
        int lane = idx & 63;
        int cb   = (idx >> 6) & 7;
        int kc   = (idx >> 9) & 3;
        int rel  = idx >> 11;
        float wc[NB];
        #pragma unroll
        for (int b = 0; b < NB; b++) wc[b] = wcomp1[rel * NB + b];
        int o  = cb * 16 + (lane & 15);
        int i0 = kc * 32 + (lane >> 4) * 8;
        short8 v;
        #pragma unroll
        for (int e = 0; e < 8; e++) {
            int i = i0 + e;
            float a = 0.f;
            #pragma unroll
            for (int b = 0; b < NB; b++) a += wc[b] * basis1[(b * D + i) * D + o];
            v[e] = (short)f2bf(a);
        }
        *((short8*)W1b + idx) = v;
    }
}

__global__ __launch_bounds__(1024) void k_hist(
        const int* __restrict__ dst, const int* __restrict__ et,
        int* __restrict__ cnt2) {
    int i = blockIdx.x * 1024 + threadIdx.x;
    if (i < NE) {
        int d = dst[i];
        int key = (d >> 6) * 1280 + et[i] * 64 + (d & 63);
        atomicAdd(&cnt2[key], 1);
    }
}

__global__ __launch_bounds__(1024) void k_scan1(const int* __restrict__ cnt2,
                                                int* __restrict__ boff2,
                                                int* __restrict__ bsum) {
    __shared__ int ws[16];
    int t = threadIdx.x, lane = t & 63, wv = t >> 6;
    int i = blockIdx.x * 1024 + t;
    int v = (i < NBKT) ? cnt2[i] : 0;
    int inc = v;
    for (int dd = 1; dd < 64; dd <<= 1) {
        int u = __shfl_up(inc, dd);
        if (lane >= dd) inc += u;
    }
    if (lane == 63) ws[wv] = inc;
    __syncthreads();
    if (t == 0) { int a = 0; for (int j = 0; j < 16; j++) { int x = ws[j]; ws[j] = a; a += x; } }
    __syncthreads();
    int ex = ws[wv] + inc - v;
    if (i < NBKT) boff2[i] = ex;
    if (t == 1023) bsum[blockIdx.x] = ex + v;
}

__global__ __launch_bounds__(1024) void k_scan2(int* __restrict__ bsum) {
    __shared__ int ws[16];
    int t = threadIdx.x, lane = t & 63, wv = t >> 6;
    int v = (t < NSB) ? bsum[t] : 0;
    int inc = v;
    for (int dd = 1; dd < 64; dd <<= 1) {
        int u = __shfl_up(inc, dd);
        if (lane >= dd) inc += u;
    }
    if (lane == 63) ws[wv] = inc;
    __syncthreads();
    if (t == 0) { int a = 0; for (int j = 0; j < 16; j++) { int x = ws[j]; ws[j] = a; a += x; } }
    __syncthreads();
    if (t < NSB) bsum[t] = ws[wv] + inc - v;
}

__global__ __launch_bounds__(1024) void k_scan3(int* __restrict__ boff2,
                                                const int* __restrict__ bsum,
                                                int* __restrict__ gcur2) {
    int i = blockIdx.x * 1024 + threadIdx.x;
    if (i < NBKT) {
        int f = boff2[i] + bsum[i >> 10];
        boff2[i] = f;
        gcur2[i] = f;
    }
    if (i == 0) boff2[NBKT] = NE;
}

__global__ __launch_bounds__(1024) void k_scatter(
        const int* __restrict__ src, const int* __restrict__ dst,
        const int* __restrict__ et, int* __restrict__ gcur2,
        int* __restrict__ epack) {
    int i = blockIdx.x * 1024 + threadIdx.x;
    if (i < NE) {
        int d = dst[i];
        int key = (d >> 6) * 1280 + et[i] * 64 + (d & 63);
        int pos = atomicAdd(&gcur2[key], 1);
        epack[pos] = src[i];
    }
}

__global__ __launch_bounds__(512) void k_h1(const int* __restrict__ cnt2,
                                            const float* __restrict__ W0,
                                            const float* __restrict__ bias0,
                                            unsigned short* __restrict__ h1b) {
    __shared__ float cs[NR * 64];
    __shared__ float w0s[NR * D];
    int t = threadIdx.x, tile = blockIdx.x;
    for (int i = t; i < NR * 64; i += 512) cs[i] = (float)cnt2[tile * 1280 + i];
    for (int i = t; i < NR * D; i += 512) w0s[i] = W0[i];
    __syncthreads();
    int nl = t >> 3, cg = t & 7;
    int n = tile * 64 + nl;
    if (n < NN) {
        float a[16];
        #pragma unroll
        for (int j = 0; j < 16; j++) a[j] = bias0[cg * 16 + j];
        for (int r = 0; r < NR; r++) {
            float c = cs[r * 64 + nl];
            #pragma unroll
            for (int j = 0; j < 16; j++) a[j] += c * w0s[r * D + cg * 16 + j];
        }
        short8 o0, o1;
        #pragma unroll
        for (int j = 0; j < 8; j++) {
            o0[j] = (short)f2bf(fmaxf(a[j], 0.f));
            o1[j] = (short)f2bf(fmaxf(a[8 + j], 0.f));
        }
        *((short8*)(h1b + n * D + cg * 16))     = o0;
        *((short8*)(h1b + n * D + cg * 16 + 8)) = o1;
    }
}

// Mega v7: one block per 64-dst tile, 8 waves, 4 blocks/CU.
// Chunk stream over (rel, 32-edge chunk) with a depth-2 ASYNC pipeline:
//   issue glds(k+1) -> Raw[buf^1]   (1 KB per wave, pre-swizzled global src)
//   s_waitcnt vmcnt(1)              (chunk k arrived; k+1 stays in flight)
//   barrier; reduce chunk k from Raw[buf] (XOR-swizzled reads, ~8cy floor)
//   rel end: publish bf16 Sl (swizzled); barrier; 16 MFMA/wave (B from W1b/L2)
//   else:    barrier
// epk (edge src ids) and ooffs staged once in LDS as ushort so the vmem
// stream contains only glds + B loads -> vmcnt(1) is provably sufficient.
__global__ __launch_bounds__(512, 8) void k_mega(
        const int* __restrict__ epack, const int* __restrict__ boff2,
        const unsigned short* __restrict__ h1b,
        const unsigned short* __restrict__ W1b,
        const float* __restrict__ bias1, const float* __restrict__ lin_w,
        const float* __restrict__ lin_b, float* __restrict__ out) {
    __shared__ __align__(16) char lds[32768];      // Raw0 8K | Raw1 8K | Sl 16K
    __shared__ unsigned short ooffs[1281];         // bucket offsets rel. to tb
    __shared__ unsigned short epk[1600];           // tile's src ids (<50000)

    int t = threadIdx.x, tile = blockIdx.x;
    int wave = t >> 6, lane = t & 63;
    int dl = t >> 3, cg = t & 7;                   // reduce role
    int rb = wave & 3, chh = wave >> 2;            // mfma role
    int row = lane & 15, gg = lane >> 4;
    int arow = rb * 16 + row;
    int rowi = (wave << 2) + (lane >> 4);          // glds: chunk row 0..31
    int parti = lane & 15;                         // glds: 16B part 0..15

    short8* Sl8 = (short8*)(lds + 16384);

    // ---- prologue: stage ooffs + epk ----
    int kbase = tile * 1280;
    int tb = boff2[kbase];
    for (int i = t; i < 1281; i += 512)
        ooffs[i] = (unsigned short)(boff2[kbase + i] - tb);
    __syncthreads();
    int nE = ooffs[1280];
    int nEc = min(nE, 1600);
    for (int i = t; i < nEc; i += 512) epk[i] = (unsigned short)epack[tb + i];
    __syncthreads();

    f32x4 acc[4];
    #pragma unroll
    for (int j = 0; j < 4; j++) acc[j] = (f32x4){0.f, 0.f, 0.f, 0.f};
    float s[16];

    // ---- chunk walk init ----
    int r = 0;
    while (r < NR && ooffs[r * 64] == ooffs[r * 64 + 64]) r++;
    int c = 0, buf = 0;

    // issue chunk 0
    if (r < NR) {
        int rbase = ooffs[r * 64];
        int cnt = ooffs[r * 64 + 64] - rbase;
        int node = (rowi < cnt) ? (int)epk[min(rbase + rowi, 1599)] : 0;
        const char* g = (const char*)h1b + (size_t)node * 256
                      + ((parti ^ (rowi & 15)) << 4);
        gload16(g, lds + (size_t)wave * 1024);
    }

    while (r < NR) {
        int rbase = ooffs[r * 64];
        int cnt = ooffs[r * 64 + 64] - rbase;
        bool relend = ((c + 1) * 32 >= cnt);
        int rn = r, cn = c + 1;
        if (relend) {
            rn = r + 1;
            while (rn < NR && ooffs[rn * 64] == ooffs[rn * 64 + 64]) rn++;
            cn = 0;
        }
        bool have_next = (rn < NR);
        if (have_next) {
            int rbn = ooffs[rn * 64];
            int cntn = ooffs[rn * 64 + 64] - rbn;
            int node = (cn * 32 + rowi < cntn)
                     ? (int)epk[min(rbn + cn * 32 + rowi, 1599)] : 0;
            const char* g = (const char*)h1b + (size_t)node * 256
                          + ((parti ^ (rowi & 15)) << 4);
            gload16(g, lds + (buf ^ 1) * 8192 + (size_t)wave * 1024);
            asm volatile("s_waitcnt vmcnt(1)" ::: "memory");
        } else {
            asm volatile("s_waitcnt vmcnt(0)" ::: "memory");
        }
        __syncthreads();                           // chunk k visible to all

        // reduce chunk k from Raw[buf]
        if (c == 0) {
            #pragma unroll
            for (int k = 0; k < 16; k++) s[k] = 0.f;
        }
        {
            const short8* RawB = (const short8*)(lds + buf * 8192);
            int cb0 = c * 32;
            int o0 = (int)ooffs[r * 64 + dl] - rbase;
            int o1 = (int)ooffs[r * 64 + dl + 1] - rbase;
            int lo = max(o0 - cb0, 0);
            int hi = min(o1 - cb0, min(32, cnt - cb0));
            for (int p = lo; p < hi; p++) {
                int key = p & 15;
                short8 w0 = RawB[p * 16 + ((2 * cg) ^ key)];
                short8 w1 = RawB[p * 16 + ((2 * cg + 1) ^ key)];
                #pragma unroll
                for (int k = 0; k < 8; k++) {
                    s[k]     += bf2f((unsigned short)w0[k]);
                    s[8 + k] += bf2f((unsigned short)w1[k]);
                }
            }
        }

        if (relend) {
            // publish swizzled bf16 S-tile
            short8 p0, p1;
            #pragma unroll
            for (int k = 0; k < 8; k++) {
                p0[k] = (short)f2bf(s[k]);
                p1[k] = (short)f2bf(s[8 + k]);
            }
            Sl8[dl * 16 + ((cg * 2)     ^ (dl & 15))] = p0;
            Sl8[dl * 16 + ((cg * 2 + 1) ^ (dl & 15))] = p1;
            __syncthreads();                       // Sl ready + reduce(k) done
            const short8* Wg8 = (const short8*)W1b + r * 2048;
            #pragma unroll
            for (int kc = 0; kc < 4; kc++) {
                short8 a = Sl8[arow * 16 + ((kc * 4 + gg) ^ (arow & 15))];
                #pragma unroll
                for (int j = 0; j < 4; j++) {
                    short8 b = Wg8[(kc * 8 + chh * 4 + j) * 64 + lane];
                    acc[j] = __builtin_amdgcn_mfma_f32_16x16x32_bf16(a, b, acc[j], 0, 0, 0);
                }
            }
        } else {
            __syncthreads();                       // reduce(k) done -> buf free
        }
        r = rn; c = cn; buf ^= 1;
    }

    __syncthreads();                               // all Sl reads done
    // epilogue part 1: relu(acc + bias1) -> LDS f32 (aliases Raw+Sl, 32 KB)
    float* aggf = (float*)lds;
    #pragma unroll
    for (int j = 0; j < 4; j++) {
        int col = (chh * 4 + j) * 16 + row;
        float b1 = bias1[col];
        #pragma unroll
        for (int reg = 0; reg < 4; reg++) {
            int er = rb * 16 + gg * 4 + reg;
            aggf[er * D + col] = fmaxf(acc[j][reg] + b1, 0.f);
        }
    }
    __syncthreads();
    // epilogue part 2: linear 128 -> 64
    for (int dd = wave; dd < 64; dd += 8) {
        int d = tile * 64 + dd;
        if (d < NN) {
            float a = lin_b[lane];
            #pragma unroll 8
            for (int k = 0; k < D; k++)
                a += aggf[dd * D + k] * lin_w[k * DO + lane];
            out[d * DO + lane] = a;
        }
    }
}

extern "C" void kernel_launch(void* const* d_in, const int* in_sizes, int n_in,
                              void* d_out, int out_size, void* d_ws, size_t ws_size,
                              hipStream_t stream) {
    const int*   src    = (const int*)d_in[0];
    const int*   dst    = (const int*)d_in[1];
    const int*   et     = (const int*)d_in[2];
    const float* basis0 = (const float*)d_in[4];
    const float* wcomp0 = (const float*)d_in[5];
    const float* bias0  = (const float*)d_in[6];
    const float* basis1 = (const float*)d_in[7];
    const float* wcomp1 = (const float*)d_in[8];
    const float* bias1  = (const float*)d_in[9];
    const float* lin_w  = (const float*)d_in[10];
    const float* lin_b  = (const float*)d_in[11];
    float* out = (float*)d_out;

    char* ws = (char*)d_ws;
    int*            cnt2  = (int*)           (ws + 0);
    int*            bsum  = (int*)           (ws + 4003840);
    int*            boff2 = (int*)           (ws + 4007808);
    int*            gcur2 = (int*)           (ws + 8011712);
    float*          W0    = (float*)         (ws + 12015616);
    unsigned short* W1b   = (unsigned short*)(ws + 12025856);
    unsigned short* h1b   = (unsigned short*)(ws + 12681216);
    int*            epack = (int*)           (ws + 25481216);

    hipMemsetAsync(ws, 0, 4003840, stream);   // zero cnt2

    k_weights<<<160, 256, 0, stream>>>(basis0, wcomp0, basis1, wcomp1, W0, W1b);
    k_hist<<<782, 1024, 0, stream>>>(dst, et, cnt2);
    k_scan1<<<NSB, 1024, 0, stream>>>(cnt2, boff2, bsum);
    k_scan2<<<1, 1024, 0, stream>>>(bsum);
    k_scan3<<<NSB, 1024, 0, stream>>>(boff2, bsum, gcur2);
    k_h1<<<NT, 512, 0, stream>>>(cnt2, W0, bias0, h1b);
    k_scatter<<<782, 1024, 0, stream>>>(src, dst, et, gcur2, epack);
    k_mega<<<NT, 512, 0, stream>>>(epack, boff2, h1b, W1b, bias1, lin_w, lin_b, out);
}

// Round 10
// 314.428 us; speedup vs baseline: 1.2644x; 1.2644x over previous
//
#include <hip/hip_runtime.h>
#include <hip/hip_bf16.h>

#define NN 50000      // nodes
#define NE 800000     // edges
#define NR 20         // relations
#define NB 8          // bases
#define D  128        // hidden dim
#define DO 64         // output dim
#define NT 782        // ceil(NN/64) dst tiles (bucket space granularity)
#define NST 3125      // NN/16 subtiles (k_mega grid) -- exact, no remainder
#define NBKT (NT*1280) // (tile, rel, dl) buckets = 1,000,960
#define NSB 978       // ceil(NBKT/1024)

typedef __attribute__((ext_vector_type(8))) short short8;
typedef __attribute__((ext_vector_type(4))) float f32x4;

__device__ inline unsigned short f2bf(float f) {
    __hip_bfloat16 h = __float2bfloat16(f);
    return *reinterpret_cast<unsigned short*>(&h);
}
__device__ inline float bf2f(unsigned short u) {
    unsigned x = ((unsigned)u) << 16;
    float f;
    __builtin_memcpy(&f, &x, 4);
    return f;
}

// ---------------------------------------------------------------------------
// ws layout (bytes): unchanged
//   [0        ..  4,003,840) cnt2  | [4,003,840.. 4,007,752) bsum
//   [4,007,808..  8,011,652) boff2 | [8,011,712..12,015,552) gcur2
//   [12,015,616..12,025,856) W0    | [12,025,856..12,681,216) W1b
//   [12,681,216..25,481,216) h1b   | [25,481,216..28,681,216) epack
// ---------------------------------------------------------------------------

__global__ __launch_bounds__(256) void k_weights(
        const float* __restrict__ basis0, const float* __restrict__ wcomp0,
        const float* __restrict__ basis1, const float* __restrict__ wcomp1,
        float* __restrict__ W0, unsigned short* __restrict__ W1b) {
    int idx = blockIdx.x * 256 + threadIdx.x;   // 0..40959
    if (idx < NR * D) {
        int r = idx / D, o = idx % D;
        float a = 0.f;
        #pragma unroll
        for (int b = 0; b < NB; b++) a += wcomp0[r * NB + b] * basis0[b * D + o];
        W0[idx] = a;
    }
    if (idx < NR * 4 * 8 * 64) {
        int lane = idx & 63;
        int cb   = (idx >> 6) & 7;
        int kc   = (idx >> 9) & 3;
        int rel  = idx >> 11;
        float wc[NB];
        #pragma unroll
        for (int b = 0; b < NB; b++) wc[b] = wcomp1[rel * NB + b];
        int o  = cb * 16 + (lane & 15);
        int i0 = kc * 32 + (lane >> 4) * 8;
        short8 v;
        #pragma unroll
        for (int e = 0; e < 8; e++) {
            int i = i0 + e;
            float a = 0.f;
            #pragma unroll
            for (int b = 0; b < NB; b++) a += wc[b] * basis1[(b * D + i) * D + o];
            v[e] = (short)f2bf(a);
        }
        *((short8*)W1b + idx) = v;
    }
}

__global__ __launch_bounds__(1024) void k_hist(
        const int* __restrict__ dst, const int* __restrict__ et,
        int* __restrict__ cnt2) {
    int i = blockIdx.x * 1024 + threadIdx.x;
    if (i < NE) {
        int d = dst[i];
        int key = (d >> 6) * 1280 + et[i] * 64 + (d & 63);
        atomicAdd(&cnt2[key], 1);
    }
}

__global__ __launch_bounds__(1024) void k_scan1(const int* __restrict__ cnt2,
                                                int* __restrict__ boff2,
                                                int* __restrict__ bsum) {
    __shared__ int ws[16];
    int t = threadIdx.x, lane = t & 63, wv = t >> 6;
    int i = blockIdx.x * 1024 + t;
    int v = (i < NBKT) ? cnt2[i] : 0;
    int inc = v;
    for (int dd = 1; dd < 64; dd <<= 1) {
        int u = __shfl_up(inc, dd);
        if (lane >= dd) inc += u;
    }
    if (lane == 63) ws[wv] = inc;
    __syncthreads();
    if (t == 0) { int a = 0; for (int j = 0; j < 16; j++) { int x = ws[j]; ws[j] = a; a += x; } }
    __syncthreads();
    int ex = ws[wv] + inc - v;
    if (i < NBKT) boff2[i] = ex;
    if (t == 1023) bsum[blockIdx.x] = ex + v;
}

__global__ __launch_bounds__(1024) void k_scan2(int* __restrict__ bsum) {
    __shared__ int ws[16];
    int t = threadIdx.x, lane = t & 63, wv = t >> 6;
    int v = (t < NSB) ? bsum[t] : 0;
    int inc = v;
    for (int dd = 1; dd < 64; dd <<= 1) {
        int u = __shfl_up(inc, dd);
        if (lane >= dd) inc += u;
    }
    if (lane == 63) ws[wv] = inc;
    __syncthreads();
    if (t == 0) { int a = 0; for (int j = 0; j < 16; j++) { int x = ws[j]; ws[j] = a; a += x; } }
    __syncthreads();
    if (t < NSB) bsum[t] = ws[wv] + inc - v;
}

__global__ __launch_bounds__(1024) void k_scan3(int* __restrict__ boff2,
                                                const int* __restrict__ bsum,
                                                int* __restrict__ gcur2) {
    int i = blockIdx.x * 1024 + threadIdx.x;
    if (i < NBKT) {
        int f = boff2[i] + bsum[i >> 10];
        boff2[i] = f;
        gcur2[i] = f;
    }
    if (i == 0) boff2[NBKT] = NE;
}

__global__ __launch_bounds__(1024) void k_scatter(
        const int* __restrict__ src, const int* __restrict__ dst,
        const int* __restrict__ et, int* __restrict__ gcur2,
        int* __restrict__ epack) {
    int i = blockIdx.x * 1024 + threadIdx.x;
    if (i < NE) {
        int d = dst[i];
        int key = (d >> 6) * 1280 + et[i] * 64 + (d & 63);
        int pos = atomicAdd(&gcur2[key], 1);
        epack[pos] = src[i];
    }
}

__global__ __launch_bounds__(512) void k_h1(const int* __restrict__ cnt2,
                                            const float* __restrict__ W0,
                                            const float* __restrict__ bias0,
                                            unsigned short* __restrict__ h1b) {
    __shared__ float cs[NR * 64];
    __shared__ float w0s[NR * D];
    int t = threadIdx.x, tile = blockIdx.x;
    for (int i = t; i < NR * 64; i += 512) cs[i] = (float)cnt2[tile * 1280 + i];
    for (int i = t; i < NR * D; i += 512) w0s[i] = W0[i];
    __syncthreads();
    int nl = t >> 3, cg = t & 7;
    int n = tile * 64 + nl;
    if (n < NN) {
        float a[16];
        #pragma unroll
        for (int j = 0; j < 16; j++) a[j] = bias0[cg * 16 + j];
        for (int r = 0; r < NR; r++) {
            float c = cs[r * 64 + nl];
            #pragma unroll
            for (int j = 0; j < 16; j++) a[j] += c * w0s[r * D + cg * 16 + j];
        }
        short8 o0, o1;
        #pragma unroll
        for (int j = 0; j < 8; j++) {
            o0[j] = (short)f2bf(fmaxf(a[j], 0.f));
            o1[j] = (short)f2bf(fmaxf(a[8 + j], 0.f));
        }
        *((short8*)(h1b + n * D + cg * 16))     = o0;
        *((short8*)(h1b + n * D + cg * 16 + 8)) = o1;
    }
}

// Mega v8: one 128-thread (2-wave) block per 16-dst SUBTILE. ~14 KB LDS ->
// 10-11 blocks/CU (20-22 waves): latency hidden by TLP, not manual pipelining.
// Per relation r (avg 12.8 edges):
//   stage: <=32 edge rows -> Raw (pad-17 chunks; plain loads, edge id read
//          direct from L2-hot epack); barrier;
//   reduce: thread (dl 0..15, cg 0..7) segment-sums its bucket from Raw;
//   publish 16x128 bf16 Sl (chunk ^ dl swizzle); barrier;
//   MFMA: wave wv does cb = wv*4..wv*4+3, 16 MFMA, B direct from W1b (L2);
//   barrier (Sl/Raw reuse).
// acc[4] f32x4 persists across relations; fused bias/relu/linear epilogue.
__global__ __launch_bounds__(128, 5) void k_mega(
        const int* __restrict__ epack, const int* __restrict__ boff2,
        const unsigned short* __restrict__ h1b,
        const unsigned short* __restrict__ W1b,
        const float* __restrict__ bias1, const float* __restrict__ lin_w,
        const float* __restrict__ lin_b, float* __restrict__ out) {
    __shared__ __align__(16) char raw[32 * 17 * 16];   // 8704 B (also agg f32[16][128])
    __shared__ __align__(16) char slb[16 * 16 * 16];   // 4096 B swizzled S-tile
    __shared__ int ooff[NR * 17];                      // 1360 B abs bucket offsets

    int t = threadIdx.x, st = blockIdx.x;
    int tile = st >> 2, q = st & 3;
    int wv = t >> 6, lane = t & 63;
    int dl = t >> 3, cg = t & 7;                 // reduce role
    int row = lane & 15, gg = lane >> 4;         // mfma role
    short8* Raw8 = (short8*)raw;
    short8* Sl8  = (short8*)slb;

    for (int i = t; i < NR * 17; i += 128) {
        int r = i / 17, j = i - r * 17;
        ooff[i] = boff2[tile * 1280 + r * 64 + q * 16 + j];
    }
    __syncthreads();

    f32x4 acc[4];
    #pragma unroll
    for (int j = 0; j < 4; j++) acc[j] = (f32x4){0.f, 0.f, 0.f, 0.f};

    for (int r = 0; r < NR; r++) {
        int rbase = ooff[r * 17];
        int cnt = ooff[r * 17 + 16] - rbase;     // block-uniform
        if (cnt == 0) continue;
        float s[16];
        #pragma unroll
        for (int k = 0; k < 16; k++) s[k] = 0.f;
        int o0 = ooff[r * 17 + dl] - rbase;
        int o1 = ooff[r * 17 + dl + 1] - rbase;
        int nc = (cnt + 31) >> 5;

        for (int c = 0; c < nc; c++) {
            int cb0 = c * 32, m = min(32, cnt - cb0);
            if (c > 0) __syncthreads();          // prev reduce done, Raw reusable
            // stage m rows (<=4 x 16B independent loads per thread)
            for (int idx = t; idx < m * 16; idx += 128) {
                int rw = idx >> 4, part = idx & 15;
                int node = epack[rbase + cb0 + rw];
                Raw8[rw * 17 + part] =
                    *((const short8*)(h1b + (size_t)node * D) + part);
            }
            __syncthreads();                     // Raw visible
            int lo = max(o0 - cb0, 0), hi = min(o1 - cb0, m);
            for (int p = lo; p < hi; p++) {
                short8 w0 = Raw8[p * 17 + 2 * cg];
                short8 w1 = Raw8[p * 17 + 2 * cg + 1];
                #pragma unroll
                for (int k = 0; k < 8; k++) {
                    s[k]     += bf2f((unsigned short)w0[k]);
                    s[8 + k] += bf2f((unsigned short)w1[k]);
                }
            }
        }
        // publish swizzled bf16 S-tile (16 rows x 16 chunks)
        short8 p0, p1;
        #pragma unroll
        for (int k = 0; k < 8; k++) {
            p0[k] = (short)f2bf(s[k]);
            p1[k] = (short)f2bf(s[8 + k]);
        }
        Sl8[dl * 16 + ((2 * cg)     ^ dl)] = p0;
        Sl8[dl * 16 + ((2 * cg + 1) ^ dl)] = p1;
        __syncthreads();                         // Sl ready (+ reduce done)
        // MFMA: A from Sl, B direct from L2-resident W1b fragments
        const short8* Wg8 = (const short8*)W1b + r * 2048;
        #pragma unroll
        for (int kc = 0; kc < 4; kc++) {
            short8 a = Sl8[row * 16 + ((kc * 4 + gg) ^ row)];
            #pragma unroll
            for (int j = 0; j < 4; j++) {
                short8 b = Wg8[(kc * 8 + wv * 4 + j) * 64 + lane];
                acc[j] = __builtin_amdgcn_mfma_f32_16x16x32_bf16(a, b, acc[j], 0, 0, 0);
            }
        }
        __syncthreads();                         // Sl/Raw reuse guard
    }

    // epilogue part 1: relu(acc + bias1) -> agg f32[16][128] (aliases Raw)
    float* aggf = (float*)raw;
    #pragma unroll
    for (int j = 0; j < 4; j++) {
        int col = (wv * 4 + j) * 16 + row;
        float b1 = bias1[col];
        #pragma unroll
        for (int reg = 0; reg < 4; reg++) {
            int er = gg * 4 + reg;
            aggf[er * D + col] = fmaxf(acc[j][reg] + b1, 0.f);
        }
    }
    __syncthreads();
    // epilogue part 2: linear 128 -> 64 (lane = out col; grid covers NN exactly)
    for (int dd = wv; dd < 16; dd += 2) {
        float a = lin_b[lane];
        #pragma unroll 8
        for (int k = 0; k < D; k++)
            a += aggf[dd * D + k] * lin_w[k * DO + lane];
        out[(st * 16 + dd) * DO + lane] = a;
    }
}

extern "C" void kernel_launch(void* const* d_in, const int* in_sizes, int n_in,
                              void* d_out, int out_size, void* d_ws, size_t ws_size,
                              hipStream_t stream) {
    const int*   src    = (const int*)d_in[0];
    const int*   dst    = (const int*)d_in[1];
    const int*   et     = (const int*)d_in[2];
    const float* basis0 = (const float*)d_in[4];
    const float* wcomp0 = (const float*)d_in[5];
    const float* bias0  = (const float*)d_in[6];
    const float* basis1 = (const float*)d_in[7];
    const float* wcomp1 = (const float*)d_in[8];
    const float* bias1  = (const float*)d_in[9];
    const float* lin_w  = (const float*)d_in[10];
    const float* lin_b  = (const float*)d_in[11];
    float* out = (float*)d_out;

    char* ws = (char*)d_ws;
    int*            cnt2  = (int*)           (ws + 0);
    int*            bsum  = (int*)           (ws + 4003840);
    int*            boff2 = (int*)           (ws + 4007808);
    int*            gcur2 = (int*)           (ws + 8011712);
    float*          W0    = (float*)         (ws + 12015616);
    unsigned short* W1b   = (unsigned short*)(ws + 12025856);
    unsigned short* h1b   = (unsigned short*)(ws + 12681216);
    int*            epack = (int*)           (ws + 25481216);

    hipMemsetAsync(ws, 0, 4003840, stream);   // zero cnt2

    k_weights<<<160, 256, 0, stream>>>(basis0, wcomp0, basis1, wcomp1, W0, W1b);
    k_hist<<<782, 1024, 0, stream>>>(dst, et, cnt2);
    k_scan1<<<NSB, 1024, 0, stream>>>(cnt2, boff2, bsum);
    k_scan2<<<1, 1024, 0, stream>>>(bsum);
    k_scan3<<<NSB, 1024, 0, stream>>>(boff2, bsum, gcur2);
    k_h1<<<NT, 512, 0, stream>>>(cnt2, W0, bias0, h1b);
    k_scatter<<<782, 1024, 0, stream>>>(src, dst, et, gcur2, epack);
    k_mega<<<NST, 128, 0, stream>>>(epack, boff2, h1b, W1b, bias1, lin_w, lin_b, out);
}

// Round 11
// 284.737 us; speedup vs baseline: 1.3962x; 1.1043x over previous
//
#include <hip/hip_runtime.h>
#include <hip/hip_bf16.h>

#define NN 50000      // nodes
#define NE 800000     // edges
#define NR 20         // relations
#define NB 8          // bases
#define D  128        // hidden dim
#define DO 64         // output dim
#define NT 782        // ceil(NN/64) dst tiles (bucket space granularity)
#define NST 3125      // NN/16 subtiles (k_mega grid) -- exact
#define NBKT (NT*1280) // (tile, rel, dl) buckets = 1,000,960
#define NSB 978       // ceil(NBKT/1024)

typedef __attribute__((ext_vector_type(8))) short short8;
typedef __attribute__((ext_vector_type(4))) float f32x4;

__device__ inline unsigned short f2bf(float f) {
    __hip_bfloat16 h = __float2bfloat16(f);
    return *reinterpret_cast<unsigned short*>(&h);
}
__device__ inline float bf2f(unsigned short u) {
    unsigned x = ((unsigned)u) << 16;
    float f;
    __builtin_memcpy(&f, &x, 4);
    return f;
}

// ---------------------------------------------------------------------------
// ws layout (bytes):
//   [0        ..  4,003,840) cnt2  | [4,003,840.. 4,007,752) bsum
//   [4,007,808..  8,011,652) boff2 | [8,011,712..12,015,552) gcur2
//   [12,015,616..12,025,856) W0    | [12,025,856..12,681,216) W1b
//   [12,681,216..25,481,216) h1b   | [25,481,216..28,681,216) epack
//   [28,681,216..28,697,600) linWb (lin_w in B-fragment order, bf16)
// ---------------------------------------------------------------------------

// W0, W1b (r2-verified fragment order), and linWb:
//   linWb task fr = kc*4 + nt (<16), lane: elem e =
//     lin_w[kc*32 + (lane>>4)*8 + e][nt*16 + (lane&15)]
__global__ __launch_bounds__(256) void k_weights(
        const float* __restrict__ basis0, const float* __restrict__ wcomp0,
        const float* __restrict__ basis1, const float* __restrict__ wcomp1,
        const float* __restrict__ lin_w,
        float* __restrict__ W0, unsigned short* __restrict__ W1b,
        unsigned short* __restrict__ linWb) {
    int idx = blockIdx.x * 256 + threadIdx.x;   // 0..40959
    if (idx < NR * D) {
        int r = idx / D, o = idx % D;
        float a = 0.f;
        #pragma unroll
        for (int b = 0; b < NB; b++) a += wcomp0[r * NB + b] * basis0[b * D + o];
        W0[idx] = a;
    }
    if (idx < 16 * 64) {
        int lane = idx & 63, fr = idx >> 6;
        int kc = fr >> 2, nt = fr & 3;
        int i0 = kc * 32 + (lane >> 4) * 8;
        int o = nt * 16 + (lane & 15);
        short8 v;
        #pragma unroll
        for (int e = 0; e < 8; e++) v[e] = (short)f2bf(lin_w[(i0 + e) * DO + o]);
        *((short8*)linWb + idx) = v;
    }
    if (idx < NR * 4 * 8 * 64) {
        int lane = idx & 63;
        int cb   = (idx >> 6) & 7;
        int kc   = (idx >> 9) & 3;
        int rel  = idx >> 11;
        float wc[NB];
        #pragma unroll
        for (int b = 0; b < NB; b++) wc[b] = wcomp1[rel * NB + b];
        int o  = cb * 16 + (lane & 15);
        int i0 = kc * 32 + (lane >> 4) * 8;
        short8 v;
        #pragma unroll
        for (int e = 0; e < 8; e++) {
            int i = i0 + e;
            float a = 0.f;
            #pragma unroll
            for (int b = 0; b < NB; b++) a += wc[b] * basis1[(b * D + i) * D + o];
            v[e] = (short)f2bf(a);
        }
        *((short8*)W1b + idx) = v;
    }
}

__global__ __launch_bounds__(1024) void k_hist(
        const int* __restrict__ dst, const int* __restrict__ et,
        int* __restrict__ cnt2) {
    int i = blockIdx.x * 1024 + threadIdx.x;
    if (i < NE) {
        int d = dst[i];
        int key = (d >> 6) * 1280 + et[i] * 64 + (d & 63);
        atomicAdd(&cnt2[key], 1);
    }
}

__global__ __launch_bounds__(1024) void k_scan1(const int* __restrict__ cnt2,
                                                int* __restrict__ boff2,
                                                int* __restrict__ bsum) {
    __shared__ int ws[16];
    int t = threadIdx.x, lane = t & 63, wv = t >> 6;
    int i = blockIdx.x * 1024 + t;
    int v = (i < NBKT) ? cnt2[i] : 0;
    int inc = v;
    for (int dd = 1; dd < 64; dd <<= 1) {
        int u = __shfl_up(inc, dd);
        if (lane >= dd) inc += u;
    }
    if (lane == 63) ws[wv] = inc;
    __syncthreads();
    if (t == 0) { int a = 0; for (int j = 0; j < 16; j++) { int x = ws[j]; ws[j] = a; a += x; } }
    __syncthreads();
    int ex = ws[wv] + inc - v;
    if (i < NBKT) boff2[i] = ex;
    if (t == 1023) bsum[blockIdx.x] = ex + v;
}

__global__ __launch_bounds__(1024) void k_scan2(int* __restrict__ bsum) {
    __shared__ int ws[16];
    int t = threadIdx.x, lane = t & 63, wv = t >> 6;
    int v = (t < NSB) ? bsum[t] : 0;
    int inc = v;
    for (int dd = 1; dd < 64; dd <<= 1) {
        int u = __shfl_up(inc, dd);
        if (lane >= dd) inc += u;
    }
    if (lane == 63) ws[wv] = inc;
    __syncthreads();
    if (t == 0) { int a = 0; for (int j = 0; j < 16; j++) { int x = ws[j]; ws[j] = a; a += x; } }
    __syncthreads();
    if (t < NSB) bsum[t] = ws[wv] + inc - v;
}

__global__ __launch_bounds__(1024) void k_scan3(int* __restrict__ boff2,
                                                const int* __restrict__ bsum,
                                                int* __restrict__ gcur2) {
    int i = blockIdx.x * 1024 + threadIdx.x;
    if (i < NBKT) {
        int f = boff2[i] + bsum[i >> 10];
        boff2[i] = f;
        gcur2[i] = f;
    }
    if (i == 0) boff2[NBKT] = NE;
}

__global__ __launch_bounds__(1024) void k_scatter(
        const int* __restrict__ src, const int* __restrict__ dst,
        const int* __restrict__ et, int* __restrict__ gcur2,
        int* __restrict__ epack) {
    int i = blockIdx.x * 1024 + threadIdx.x;
    if (i < NE) {
        int d = dst[i];
        int key = (d >> 6) * 1280 + et[i] * 64 + (d & 63);
        int pos = atomicAdd(&gcur2[key], 1);
        epack[pos] = src[i];
    }
}

__global__ __launch_bounds__(512) void k_h1(const int* __restrict__ cnt2,
                                            const float* __restrict__ W0,
                                            const float* __restrict__ bias0,
                                            unsigned short* __restrict__ h1b) {
    __shared__ float cs[NR * 64];
    __shared__ float w0s[NR * D];
    int t = threadIdx.x, tile = blockIdx.x;
    for (int i = t; i < NR * 64; i += 512) cs[i] = (float)cnt2[tile * 1280 + i];
    for (int i = t; i < NR * D; i += 512) w0s[i] = W0[i];
    __syncthreads();
    int nl = t >> 3, cg = t & 7;
    int n = tile * 64 + nl;
    if (n < NN) {
        float a[16];
        #pragma unroll
        for (int j = 0; j < 16; j++) a[j] = bias0[cg * 16 + j];
        for (int r = 0; r < NR; r++) {
            float c = cs[r * 64 + nl];
            #pragma unroll
            for (int j = 0; j < 16; j++) a[j] += c * w0s[r * D + cg * 16 + j];
        }
        short8 o0, o1;
        #pragma unroll
        for (int j = 0; j < 8; j++) {
            o0[j] = (short)f2bf(fmaxf(a[j], 0.f));
            o1[j] = (short)f2bf(fmaxf(a[8 + j], 0.f));
        }
        *((short8*)(h1b + n * D + cg * 16))     = o0;
        *((short8*)(h1b + n * D + cg * 16 + 8)) = o1;
    }
}

// Mega v9: one 256-thr block per 16-dst subtile; the 4 waves K-SPLIT the GEMM
// (wave w owns h1 cols / W1 rows w*32..w*32+31) and run the whole 20-rel loop
// with ZERO __syncthreads -- wave-private LDS slices, lgkmcnt-only ordering.
// Per rel per wave: gather quarter-rows (1 load + 1 ds_write PER LANE),
// light segment-sum (<=8 cols/lane), 1-write publish, 8 MFMA (kc=w).
// Barriers only at the final acc-merge; epilogue linear is MFMA too.
__global__ __launch_bounds__(256, 4) void k_mega(
        const int* __restrict__ epack, const int* __restrict__ boff2,
        const unsigned short* __restrict__ h1b,
        const unsigned short* __restrict__ W1b,
        const unsigned short* __restrict__ linWb,
        const float* __restrict__ bias1, const float* __restrict__ lin_b,
        float* __restrict__ out) {
    // main loop: 4 wave-slices of 2560 B (Raw 16x5 + Sl 16x5 short8, pad-5)
    // merge:     accb f32[4][2048] (32 KB, aliases slices) + Af bf16 16x136
    __shared__ __align__(16) char lds[32768 + 4480];

    int t = threadIdx.x, st = blockIdx.x;
    int wv = t >> 6, lane = t & 63;
    int tile = st >> 2, q = st & 3;
    int dl = lane & 15, half = lane >> 4;    // reduce/mfma roles
    int se = lane >> 2, pp = lane & 3;       // stage role: edge, 16B part

    short8* Raw8 = (short8*)(lds + wv * 2560);
    short8* Sl8  = Raw8 + 80;

    f32x4 acc[8];
    #pragma unroll
    for (int j = 0; j < 8; j++) acc[j] = (f32x4){0.f, 0.f, 0.f, 0.f};

    int kb = tile * 1280 + q * 16;
    int o0 = boff2[kb + dl], o1 = boff2[kb + dl + 1];

    for (int r = 0; r < NR; r++) {
        int rbase = __shfl(o0, 0);
        int rend  = __shfl(o1, 15);
        int cnt = rend - rbase;
        // prefetch next rel's bucket bounds
        int o0n = 0, o1n = 0;
        if (r + 1 < NR) {
            o0n = boff2[kb + (r + 1) * 64 + dl];
            o1n = boff2[kb + (r + 1) * 64 + dl + 1];
        }
        if (cnt > 0) {
            float s[8];
            #pragma unroll
            for (int k = 0; k < 8; k++) s[k] = 0.f;
            int b0 = o0 - rbase, b1 = o1 - rbase;

            for (int cb0 = 0; cb0 < cnt; cb0 += 16) {
                int m = min(16, cnt - cb0);
                if (se < m) {
                    int node = epack[rbase + cb0 + se];
                    short8 v = *((const short8*)(h1b + (size_t)node * D)
                                 + wv * 4 + pp);
                    Raw8[se * 5 + pp] = v;
                }
                asm volatile("s_waitcnt lgkmcnt(0)" ::: "memory");
                int lo = max(b0 - cb0, 0), hi = min(b1 - cb0, m);
                for (int p = lo; p < hi; p++) {
                    short8 w = Raw8[p * 5 + half];
                    #pragma unroll
                    for (int k = 0; k < 8; k++) s[k] += bf2f((unsigned short)w[k]);
                }
            }
            // publish this wave's 16x32 S-quarter (1 write/lane)
            short8 pb;
            #pragma unroll
            for (int k = 0; k < 8; k++) pb[k] = (short)f2bf(s[k]);
            Sl8[dl * 5 + half] = pb;
            asm volatile("s_waitcnt lgkmcnt(0)" ::: "memory");
            // 8 MFMA, kc = wv quarter; B-frags from L2-resident W1b
            short8 a = Sl8[dl * 5 + half];   // A[m=dl][k=half*8+e] (local quarter)
            const short8* Wg8 = (const short8*)W1b + r * 2048 + wv * 8 * 64;
            #pragma unroll
            for (int cbt = 0; cbt < 8; cbt++) {
                short8 b = Wg8[cbt * 64 + lane];
                acc[cbt] = __builtin_amdgcn_mfma_f32_16x16x32_bf16(a, b, acc[cbt], 0, 0, 0);
            }
        }
        o0 = o0n; o1 = o1n;
        kb = tile * 1280 + q * 16;   // keep kb base (o-loads use r+1 offset)
    }

    // ---- merge the 4 K-partial accs (the only cross-wave phase) ----
    __syncthreads();                          // all waves done with slices
    float* ldsf = (float*)lds;
    #pragma unroll
    for (int cbt = 0; cbt < 8; cbt++) {
        #pragma unroll
        for (int reg = 0; reg < 4; reg++) {
            ldsf[wv * 2048 + (half * 4 + reg) * D + cbt * 16 + dl] = acc[cbt][reg];
        }
    }
    __syncthreads();
    unsigned short* Af = (unsigned short*)(lds + 32768);
    for (int i = t; i < 2048; i += 256) {
        float v = ldsf[i] + ldsf[2048 + i] + ldsf[4096 + i] + ldsf[6144 + i];
        int row = i >> 7, col = i & 127;
        Af[row * 136 + col] = f2bf(fmaxf(v + bias1[col], 0.f));
    }
    __syncthreads();
    // epilogue GEMM: out16x64 = Af @ lin_w ; wave wv does out-col tile nt=wv
    f32x4 ao = (f32x4){0.f, 0.f, 0.f, 0.f};
    #pragma unroll
    for (int kc = 0; kc < 4; kc++) {
        short8 a = *(const short8*)(Af + dl * 136 + kc * 32 + half * 8);
        short8 b = *((const short8*)linWb + (kc * 4 + wv) * 64 + lane);
        ao = __builtin_amdgcn_mfma_f32_16x16x32_bf16(a, b, ao, 0, 0, 0);
    }
    float lb = lin_b[wv * 16 + dl];
    #pragma unroll
    for (int reg = 0; reg < 4; reg++) {
        out[(st * 16 + half * 4 + reg) * DO + wv * 16 + dl] = ao[reg] + lb;
    }
}

extern "C" void kernel_launch(void* const* d_in, const int* in_sizes, int n_in,
                              void* d_out, int out_size, void* d_ws, size_t ws_size,
                              hipStream_t stream) {
    const int*   src    = (const int*)d_in[0];
    const int*   dst    = (const int*)d_in[1];
    const int*   et     = (const int*)d_in[2];
    const float* basis0 = (const float*)d_in[4];
    const float* wcomp0 = (const float*)d_in[5];
    const float* bias0  = (const float*)d_in[6];
    const float* basis1 = (const float*)d_in[7];
    const float* wcomp1 = (const float*)d_in[8];
    const float* bias1  = (const float*)d_in[9];
    const float* lin_w  = (const float*)d_in[10];
    const float* lin_b  = (const float*)d_in[11];
    float* out = (float*)d_out;

    char* ws = (char*)d_ws;
    int*            cnt2  = (int*)           (ws + 0);
    int*            bsum  = (int*)           (ws + 4003840);
    int*            boff2 = (int*)           (ws + 4007808);
    int*            gcur2 = (int*)           (ws + 8011712);
    float*          W0    = (float*)         (ws + 12015616);
    unsigned short* W1b   = (unsigned short*)(ws + 12025856);
    unsigned short* h1b   = (unsigned short*)(ws + 12681216);
    int*            epack = (int*)           (ws + 25481216);
    unsigned short* linWb = (unsigned short*)(ws + 28681216);

    hipMemsetAsync(ws, 0, 4003840, stream);   // zero cnt2

    k_weights<<<160, 256, 0, stream>>>(basis0, wcomp0, basis1, wcomp1, lin_w,
                                       W0, W1b, linWb);
    k_hist<<<782, 1024, 0, stream>>>(dst, et, cnt2);
    k_scan1<<<NSB, 1024, 0, stream>>>(cnt2, boff2, bsum);
    k_scan2<<<1, 1024, 0, stream>>>(bsum);
    k_scan3<<<NSB, 1024, 0, stream>>>(boff2, bsum, gcur2);
    k_h1<<<NT, 512, 0, stream>>>(cnt2, W0, bias0, h1b);
    k_scatter<<<782, 1024, 0, stream>>>(src, dst, et, gcur2, epack);
    k_mega<<<NST, 256, 0, stream>>>(epack, boff2, h1b, W1b, linWb,
                                    bias1, lin_b, out);
}